// Round 4
// baseline (882.631 us; speedup 1.0000x reference)
//
#include <hip/hip_runtime.h>

#define N_DRUG 50000
#define F_DRUG 256
#define E_DRUG 1000000
#define N_DIS  20000
#define F_DIS  128
#define E_DIS  640000
#define NHID   64

#define NBKT 512   // padded bucket-array size (actual buckets: 391 drug, 313 dis)

typedef __bf16 bf16x8 __attribute__((ext_vector_type(8)));
typedef float  f32x4  __attribute__((ext_vector_type(4)));

__device__ inline float bf2f(unsigned short u) {
    union { unsigned int i; float f; } c;
    c.i = ((unsigned int)u) << 16;
    return c.f;
}

// ---------------- prepack W -> bf16, MFMA-B-fragment layout ----------------
__global__ void prepack_kernel(const float* __restrict__ W1, __bf16* __restrict__ Wp1, int n1,
                               const float* __restrict__ W2, __bf16* __restrict__ Wp2, int n2) {
    int i = blockIdx.x * blockDim.x + threadIdx.x;
    const float* W; __bf16* Wp; int idx;
    if (i < n1) { W = W1; Wp = Wp1; idx = i; }
    else if (i < n1 + n2) { W = W2; Wp = Wp2; idx = i - n1; }
    else return;
    int k = idx >> 6, col = idx & 63;
    Wp[((size_t)(k >> 3) * 64 + col) * 8 + (k & 7)] = (__bf16)W[idx];
}

// ---------------- MFMA GEMM: h[M,64](bf16) = bf16(x[M,K]) @ bf16(W[K,64]) ----------------
template <int K>
__global__ void __launch_bounds__(256)
mfma_gemm_kernel(const float* __restrict__ x, const __bf16* __restrict__ Wp,
                 __bf16* __restrict__ h, int M) {
    __shared__ __bf16 Wlds[K * 64];
    {
        const int4* src = (const int4*)Wp;
        int4* dst = (int4*)Wlds;
        const int nchunk = K * 64 * 2 / 16;
        for (int i = threadIdx.x; i < nchunk; i += 256) dst[i] = src[i];
    }
    __syncthreads();

    const int wid = threadIdx.x >> 6, lane = threadIdx.x & 63;
    const int l15 = lane & 15, lhi = lane >> 4;
    const int r0 = blockIdx.x * 128 + wid * 32;
    if (r0 >= M) return;

    f32x4 acc[2][4];
#pragma unroll
    for (int m = 0; m < 2; ++m)
#pragma unroll
        for (int c = 0; c < 4; ++c) acc[m][c] = {0.f, 0.f, 0.f, 0.f};

    int rowA0 = r0 + l15;
    int rowA1 = r0 + 16 + l15;
    int cr0 = rowA0 < M ? rowA0 : M - 1;
    int cr1 = rowA1 < M ? rowA1 : M - 1;
    const float* pA0 = x + (size_t)cr0 * K + lhi * 8;
    const float* pA1 = x + (size_t)cr1 * K + lhi * 8;
    const bf16x8* Wv = (const bf16x8*)Wlds;

    for (int kk = 0; kk < K; kk += 32) {
        float4 a0l = *(const float4*)(pA0 + kk);
        float4 a0h = *(const float4*)(pA0 + kk + 4);
        float4 a1l = *(const float4*)(pA1 + kk);
        float4 a1h = *(const float4*)(pA1 + kk + 4);
        bf16x8 af0, af1;
        af0[0] = (__bf16)a0l.x; af0[1] = (__bf16)a0l.y;
        af0[2] = (__bf16)a0l.z; af0[3] = (__bf16)a0l.w;
        af0[4] = (__bf16)a0h.x; af0[5] = (__bf16)a0h.y;
        af0[6] = (__bf16)a0h.z; af0[7] = (__bf16)a0h.w;
        af1[0] = (__bf16)a1l.x; af1[1] = (__bf16)a1l.y;
        af1[2] = (__bf16)a1l.z; af1[3] = (__bf16)a1l.w;
        af1[4] = (__bf16)a1h.x; af1[5] = (__bf16)a1h.y;
        af1[6] = (__bf16)a1h.z; af1[7] = (__bf16)a1h.w;
        const int kblk = (kk >> 3) + lhi;
#pragma unroll
        for (int c = 0; c < 4; ++c) {
            bf16x8 bf = Wv[kblk * 64 + c * 16 + l15];
            acc[0][c] = __builtin_amdgcn_mfma_f32_16x16x32_bf16(af0, bf, acc[0][c], 0, 0, 0);
            acc[1][c] = __builtin_amdgcn_mfma_f32_16x16x32_bf16(af1, bf, acc[1][c], 0, 0, 0);
        }
    }

#pragma unroll
    for (int m = 0; m < 2; ++m) {
        int rbase = r0 + m * 16 + lhi * 4;
#pragma unroll
        for (int c = 0; c < 4; ++c) {
            int col = c * 16 + l15;
#pragma unroll
            for (int r = 0; r < 4; ++r) {
                int row = rbase + r;
                if (row < M) h[(size_t)row * 64 + col] = (__bf16)acc[m][c][r];
            }
        }
    }
}

// ---------------- bucket machinery ----------------
__global__ void zero_bcnt_kernel(int* __restrict__ a, int* __restrict__ b) {
    int i = threadIdx.x;
    for (; i < NBKT; i += 256) { a[i] = 0; b[i] = 0; }
}

// per-block LDS-privatized bucket histogram
__global__ void __launch_bounds__(256)
bucket_hist_kernel(const int* __restrict__ ei, int E, int shift, int* __restrict__ gcnt) {
    __shared__ int h[NBKT];
    for (int i = threadIdx.x; i < NBKT; i += 256) h[i] = 0;
    __syncthreads();
    int stride = gridDim.x * 256;
    for (int i = blockIdx.x * 256 + threadIdx.x; i < E; i += stride)
        atomicAdd(&h[ei[E + i] >> shift], 1);
    __syncthreads();
    for (int i = threadIdx.x; i < NBKT; i += 256)
        if (h[i]) atomicAdd(&gcnt[i], h[i]);
}

// exclusive scan of 512 bucket counts; block 0 -> graph 1, block 1 -> graph 2
__global__ void scan_buckets_kernel(const int* __restrict__ c1, int* __restrict__ s1, int* __restrict__ cur1,
                                    const int* __restrict__ c2, int* __restrict__ s2, int* __restrict__ cur2) {
    const int* c; int* s; int* cur;
    if (blockIdx.x == 0) { c = c1; s = s1; cur = cur1; }
    else                 { c = c2; s = s2; cur = cur2; }
    int lane = threadIdx.x;   // 64 threads
    int run = 0;
    for (int ch = 0; ch < NBKT / 64; ++ch) {
        int v = c[ch * 64 + lane];
        int incl = v;
#pragma unroll
        for (int off = 1; off < 64; off <<= 1) {
            int t = __shfl_up(incl, off);
            if (lane >= off) incl += t;
        }
        int ex = run + incl - v;
        s[ch * 64 + lane] = ex;
        cur[ch * 64 + lane] = ex;
        run += __shfl(incl, 63);
    }
    if (lane == 0) s[NBKT] = run;
}

// Bin edges by bucket: local LDS reorder -> coalesced run writes.
__global__ void __launch_bounds__(256)
bin_kernel(const int* __restrict__ ei, int E, int shift,
           int* __restrict__ gcur, int2* __restrict__ binned) {
    __shared__ int hist[NBKT];
    __shared__ int excl[NBKT];
    __shared__ int gbase[NBKT];
    __shared__ int2 buf[4096];

    const int tid = threadIdx.x;
    const int base = blockIdx.x * 4096;
    const int total = min(4096, E - base);

    for (int i = tid; i < NBKT; i += 256) hist[i] = 0;
    __syncthreads();

    int2 my[16];
    int mybkt[16];
    int myloc[16];
#pragma unroll
    for (int j = 0; j < 16; ++j) {
        int e = base + j * 256 + tid;
        if (e < E) {
            int s = ei[e];
            int d = ei[E + e];
            my[j] = make_int2(s, d);
            mybkt[j] = d >> shift;
            myloc[j] = atomicAdd(&hist[mybkt[j]], 1);
        } else {
            mybkt[j] = -1;
        }
    }
    __syncthreads();

    // exclusive scan of hist[512] by wave 0
    if (tid < 64) {
        int run = 0;
        for (int ch = 0; ch < NBKT / 64; ++ch) {
            int v = hist[ch * 64 + tid];
            int incl = v;
#pragma unroll
            for (int off = 1; off < 64; off <<= 1) {
                int t = __shfl_up(incl, off);
                if (tid >= off) incl += t;
            }
            excl[ch * 64 + tid] = run + incl - v;
            run += __shfl(incl, 63);
        }
    }
    __syncthreads();

    // reserve global runs
    for (int i = tid; i < NBKT; i += 256) {
        int cnt = hist[i];
        if (cnt) gbase[i] = atomicAdd(&gcur[i], cnt);
    }
    __syncthreads();

    // reorder into LDS (bucket-grouped)
#pragma unroll
    for (int j = 0; j < 16; ++j)
        if (mybkt[j] >= 0) buf[excl[mybkt[j]] + myloc[j]] = my[j];
    __syncthreads();

    // coalesced copy-out per bucket run
    for (int s = tid; s < total; s += 256) {
        int2 p = buf[s];
        int b = p.y >> shift;
        binned[gbase[b] + (s - excl[b])] = p;
    }
}

// ---------------- bucket aggregation: LDS out-tile + ds_add_f32 ----------------
template <int ROWS>
__global__ void __launch_bounds__(256)
agg_kernel(const int2* __restrict__ binned, const int* __restrict__ bstart,
           const unsigned short* __restrict__ hbf, const float* __restrict__ bias,
           float* __restrict__ out, int N) {
    __shared__ float tile[ROWS * 64];
    const int lane = threadIdx.x & 63;
    const int w = threadIdx.x >> 6;
    const int b = blockIdx.x;

    for (int i = threadIdx.x; i < ROWS * 64; i += 256) tile[i] = 0.f;
    __syncthreads();

    const int s = bstart[b], e = bstart[b + 1];
    const int cnt = e - s;
    const int per = (cnt + 3) >> 2;
    int ws = s + w * per;
    int we = ws + per; if (we > e) we = e;

    for (int e0 = ws; e0 < we; e0 += 8) {
        int n = we - e0; if (n > 8) n = 8;
        float v[8]; int loc[8];
        for (int k = 0; k < n; ++k) {
            int2 p = binned[e0 + k];
            loc[k] = p.y & (ROWS - 1);
            v[k] = bf2f(hbf[(size_t)p.x * 64 + lane]);
        }
        for (int k = 0; k < n; ++k)
            atomicAdd(&tile[loc[k] * 64 + lane], v[k]);
    }
    __syncthreads();

    const int rowbase = b * ROWS;
    for (int r = w; r < ROWS; r += 4) {
        int row = rowbase + r;
        if (row < N) out[(size_t)row * 64 + lane] = tile[r * 64 + lane] + bias[lane];
    }
}

extern "C" void kernel_launch(void* const* d_in, const int* in_sizes, int n_in,
                              void* d_out, int out_size, void* d_ws, size_t ws_size,
                              hipStream_t stream) {
    const float* drug_x = (const float*)d_in[0];
    const float* dis_x  = (const float*)d_in[1];
    const float* W1     = (const float*)d_in[2];
    const float* b1     = (const float*)d_in[3];
    const float* W2     = (const float*)d_in[4];
    const float* b2     = (const float*)d_in[5];
    const int*   ei1    = (const int*)d_in[6];
    const int*   ei2    = (const int*)d_in[7];
    float* out = (float*)d_out;

    // workspace layout (all chunks 16B-aligned)
    char* p = (char*)d_ws;
    __bf16* h1 = (__bf16*)p;   p += (size_t)N_DRUG * NHID * 2;     // 6.40 MB
    __bf16* h2 = (__bf16*)p;   p += (size_t)N_DIS  * NHID * 2;     // 2.56 MB
    int2* bin1 = (int2*)p;     p += (size_t)E_DRUG * 8;            // 8.00 MB
    int2* bin2 = (int2*)p;     p += (size_t)E_DIS  * 8;            // 5.12 MB
    int* bcnt1   = (int*)p;    p += NBKT * 4;
    int* bstart1 = (int*)p;    p += (NBKT + 4) * 4;
    int* bcur1   = (int*)p;    p += NBKT * 4;
    int* bcnt2   = (int*)p;    p += NBKT * 4;
    int* bstart2 = (int*)p;    p += (NBKT + 4) * 4;
    int* bcur2   = (int*)p;    p += NBKT * 4;
    __bf16* Wp1 = (__bf16*)p;  p += (size_t)F_DRUG * NHID * 2;     // 32 KB
    __bf16* Wp2 = (__bf16*)p;                                      // 16 KB

    // shift: bucket = dst >> shift; ROWS = 1<<shift
    const int SH1 = 7, B1 = (N_DRUG + 127) / 128;   // 391 buckets, 128 rows
    const int SH2 = 6, B2 = (N_DIS + 63) / 64;      // 313 buckets, 64 rows

    // 1) zero bucket counters
    zero_bcnt_kernel<<<1, 256, 0, stream>>>(bcnt1, bcnt2);
    // 2) bucket histograms
    bucket_hist_kernel<<<256, 256, 0, stream>>>(ei1, E_DRUG, SH1, bcnt1);
    bucket_hist_kernel<<<160, 256, 0, stream>>>(ei2, E_DIS,  SH2, bcnt2);
    // 3) bucket scans (starts + cursors)
    scan_buckets_kernel<<<2, 64, 0, stream>>>(bcnt1, bstart1, bcur1, bcnt2, bstart2, bcur2);
    // 4) bin edges (coalesced run writes)
    bin_kernel<<<(E_DRUG + 4095) / 4096, 256, 0, stream>>>(ei1, E_DRUG, SH1, bcur1, bin1);
    bin_kernel<<<(E_DIS  + 4095) / 4096, 256, 0, stream>>>(ei2, E_DIS,  SH2, bcur2, bin2);
    // 5) prepack W + MFMA GEMMs (h in bf16)
    {
        int n1 = F_DRUG * NHID, n2 = F_DIS * NHID;
        prepack_kernel<<<(n1 + n2 + 255) / 256, 256, 0, stream>>>(W1, Wp1, n1, W2, Wp2, n2);
    }
    mfma_gemm_kernel<F_DRUG><<<(N_DRUG + 127) / 128, 256, 0, stream>>>(drug_x, Wp1, h1, N_DRUG);
    mfma_gemm_kernel<F_DIS ><<<(N_DIS  + 127) / 128, 256, 0, stream>>>(dis_x,  Wp2, h2, N_DIS);
    // 6) bucket aggregation (+bias)
    agg_kernel<128><<<B1, 256, 0, stream>>>(bin1, bstart1, (const unsigned short*)h1, b1, out, N_DRUG);
    agg_kernel<64 ><<<B2, 256, 0, stream>>>(bin2, bstart2, (const unsigned short*)h2, b2,
                                            out + (size_t)N_DRUG * NHID, N_DIS);
}